// Round 1
// baseline (963.904 us; speedup 1.0000x reference)
//
#include <hip/hip_runtime.h>
#include <hip/hip_bf16.h>
#include <cstdint>
#include <cstddef>

#define DEV_INLINE __device__ __forceinline__

typedef float  f32x4  __attribute__((ext_vector_type(4)));
typedef __bf16 bf16x8 __attribute__((ext_vector_type(8)));
typedef __bf16 bf16x4 __attribute__((ext_vector_type(4)));

static constexpr int kB = 2, kS = 2048, kD = 1024, kH = 16, kDK = 64;
static constexpr int kM  = kB * kS;        // 4096 rows
static constexpr int kNX = kM * kD;        // 4,194,304
static constexpr int kNW = kD * kD;        // 1,048,576

DEV_INLINE void gld16(void* lds, const void* g) {
  __builtin_amdgcn_global_load_lds(
      (const __attribute__((address_space(1))) unsigned int*)g,
      (__attribute__((address_space(3))) unsigned int*)lds, 16, 0, 0);
}

// ---------------- fp32 -> bf16 convert (q,k,v,Wq,Wk,Wv,Wo) ----------------
__global__ __launch_bounds__(256) void cvt_kernel(
    const float* __restrict__ q, const float* __restrict__ k, const float* __restrict__ v,
    const float* __restrict__ wq, const float* __restrict__ wk, const float* __restrict__ wv,
    const float* __restrict__ wo, __bf16* __restrict__ xb, __bf16* __restrict__ wb) {
  const int z = blockIdx.y;
  const float* src;
  __bf16* dst;
  int n;
  switch (z) {
    case 0:  src = q;  dst = xb;           n = kNX; break;
    case 1:  src = k;  dst = xb + kNX;     n = kNX; break;
    case 2:  src = v;  dst = xb + 2 * kNX; n = kNX; break;
    case 3:  src = wq; dst = wb;           n = kNW; break;
    case 4:  src = wk; dst = wb + kNW;     n = kNW; break;
    case 5:  src = wv; dst = wb + 2 * kNW; n = kNW; break;
    default: src = wo; dst = wb + 3 * kNW; n = kNW; break;
  }
  const int i = (blockIdx.x * 256 + threadIdx.x) * 4;
  if (i < n) {
    float4 f = *(const float4*)(src + i);
    bf16x4 o;
    o[0] = (__bf16)f.x; o[1] = (__bf16)f.y; o[2] = (__bf16)f.z; o[3] = (__bf16)f.w;
    *(bf16x4*)(dst + i) = o;
  }
}

// ---- GEMM core: C[m][n] = sum_k A[m][k]*W[n][k] + bias[n]; M=4096,N=1024,K=1024
// MODE 0: bf16 head-split [b,h,s,dk]  MODE 1: bf16 transposed [b,h,dk,s]  MODE 2: f32 [m][n]
template <int MODE>
DEV_INLINE void gemm_core(__bf16* As, __bf16* Bs,
                          const __bf16* __restrict__ A, const __bf16* __restrict__ W,
                          const float* __restrict__ bias, void* __restrict__ dstv) {
  const int tid = threadIdx.x;
  const int w = tid >> 6, l = tid & 63;
  const int m0 = blockIdx.y * 128, n0 = blockIdx.x * 128;
  const int wr = (w >> 1) * 64, wc = (w & 1) * 64;
  const int fr = l & 15, fc = l >> 4;
  const int srow = tid >> 2;         // staging row within 64-row chunk
  const int scol = (tid & 3) * 8;    // staging col (bf16 elems)

  f32x4 acc[4][4];
  const f32x4 z4 = {0.f, 0.f, 0.f, 0.f};
#pragma unroll
  for (int mi = 0; mi < 4; ++mi)
#pragma unroll
    for (int ni = 0; ni < 4; ++ni) acc[mi][ni] = z4;

  for (int k0 = 0; k0 < kD; k0 += 32) {
    __syncthreads();
    // stage A tile (128x32 bf16 = 8KB) and B tile via async global->LDS, 16B/lane
    gld16(As + (size_t)(w * 64) * 8,       A + (size_t)(m0 + srow) * kD + k0 + scol);
    gld16(As + (size_t)(256 + w * 64) * 8, A + (size_t)(m0 + 64 + srow) * kD + k0 + scol);
    gld16(Bs + (size_t)(w * 64) * 8,       W + (size_t)(n0 + srow) * kD + k0 + scol);
    gld16(Bs + (size_t)(256 + w * 64) * 8, W + (size_t)(n0 + 64 + srow) * kD + k0 + scol);
    __syncthreads();
    bf16x8 af[4], bfr[4];
#pragma unroll
    for (int mi = 0; mi < 4; ++mi)
      af[mi] = *(const bf16x8*)(As + (wr + mi * 16 + fr) * 32 + fc * 8);
#pragma unroll
    for (int ni = 0; ni < 4; ++ni)
      bfr[ni] = *(const bf16x8*)(Bs + (wc + ni * 16 + fr) * 32 + fc * 8);
#pragma unroll
    for (int mi = 0; mi < 4; ++mi)
#pragma unroll
      for (int ni = 0; ni < 4; ++ni)
        acc[mi][ni] = __builtin_amdgcn_mfma_f32_16x16x32_bf16(af[mi], bfr[ni], acc[mi][ni], 0, 0, 0);
  }

#pragma unroll
  for (int mi = 0; mi < 4; ++mi) {
#pragma unroll
    for (int ni = 0; ni < 4; ++ni) {
      const int col = n0 + wc + ni * 16 + fr;
      const float bb = bias[col];
#pragma unroll
      for (int r = 0; r < 4; ++r) {
        const int row = m0 + wr + mi * 16 + fc * 4 + r;  // C-layout: row=(l>>4)*4+reg, col=l&15
        const float val = acc[mi][ni][r] + bb;
        if (MODE == 2) {
          ((float*)dstv)[(size_t)row * kD + col] = val;
        } else {
          const int b = row >> 11, s = row & (kS - 1);
          const int h = col >> 6, dk = col & 63;
          size_t idx;
          if (MODE == 0) idx = ((size_t)(b * kH + h) * kS + s) * kDK + dk;
          else           idx = ((size_t)(b * kH + h) * kDK + dk) * kS + s;
          ((__bf16*)dstv)[idx] = (__bf16)val;
        }
      }
    }
  }
}

__global__ __launch_bounds__(256) void proj_kernel(
    const __bf16* __restrict__ xb, const __bf16* __restrict__ wb,
    const float* __restrict__ bq, const float* __restrict__ bk, const float* __restrict__ bv,
    __bf16* __restrict__ Qh, __bf16* __restrict__ Kh, __bf16* __restrict__ Vt) {
  __shared__ __attribute__((aligned(16))) __bf16 As[128 * 32];
  __shared__ __attribute__((aligned(16))) __bf16 Bs[128 * 32];
  const int z = blockIdx.z;
  const __bf16* A = xb + (size_t)z * kNX;
  const __bf16* W = wb + (size_t)z * kNW;
  if (z == 0)      gemm_core<0>(As, Bs, A, W, bq, Qh);
  else if (z == 1) gemm_core<0>(As, Bs, A, W, bk, Kh);
  else             gemm_core<1>(As, Bs, A, W, bv, Vt);
}

__global__ __launch_bounds__(256) void outproj_kernel(
    const __bf16* __restrict__ ctxb, const __bf16* __restrict__ wo,
    const float* __restrict__ bo, float* __restrict__ out) {
  __shared__ __attribute__((aligned(16))) __bf16 As[128 * 32];
  __shared__ __attribute__((aligned(16))) __bf16 Bs[128 * 32];
  gemm_core<2>(As, Bs, ctxb, wo, bo, out);
}

// ---------------- fused causal attention ----------------
// Block: 4 waves x 16 Q-rows = 64 rows per (bh, qt). Two passes over K-tiles of 64.
DEV_INLINE void qk_tile(const __bf16* __restrict__ Kh, size_t ktile_base,
                        bf16x8 aq0, bf16x8 aq1, int fr, int fc, f32x4 sc[4]) {
  const f32x4 z4 = {0.f, 0.f, 0.f, 0.f};
#pragma unroll
  for (int ni = 0; ni < 4; ++ni) sc[ni] = z4;
#pragma unroll
  for (int kc = 0; kc < 2; ++kc) {
    bf16x8 aq = kc ? aq1 : aq0;
#pragma unroll
    for (int ni = 0; ni < 4; ++ni) {
      // B-frag: lane holds K[n = ni*16+fr][k = kc*32 + fc*8 + j] (contiguous 16B)
      bf16x8 bk = *(const bf16x8*)(Kh + ktile_base + (size_t)(ni * 16 + fr) * kDK + kc * 32 + fc * 8);
      sc[ni] = __builtin_amdgcn_mfma_f32_16x16x32_bf16(aq, bk, sc[ni], 0, 0, 0);
    }
  }
}

__global__ __launch_bounds__(256) void attn_kernel(
    const __bf16* __restrict__ Qh, const __bf16* __restrict__ Kh,
    const __bf16* __restrict__ Vt, float* __restrict__ attnp,
    __bf16* __restrict__ ctxb) {
  // per-wave P tile, row stride 72 (pad 8) to break bank alignment; b128-aligned (144B)
  __shared__ __attribute__((aligned(16))) __bf16 Plds[4][16][72];
  const int qt = blockIdx.x, bh = blockIdx.y;
  const int tid = threadIdx.x, w = tid >> 6, l = tid & 63;
  const int fr = l & 15, fc = l >> 4;
  const int q0 = qt * 64;
  const int rowg = q0 + w * 16;
  const int nkt = qt + 1;

  // Q fragments for this wave's 16 rows (held in regs for the whole kernel)
  const __bf16* qptr = Qh + ((size_t)bh * kS + rowg + fr) * kDK + fc * 8;
  const bf16x8 aq0 = *(const bf16x8*)(qptr);
  const bf16x8 aq1 = *(const bf16x8*)(qptr + 32);

  float mrow[4], lrow[4];
#pragma unroll
  for (int r = 0; r < 4; ++r) { mrow[r] = -1.0e30f; lrow[r] = 0.f; }

  // ---- pass 1: exact row max and sum-of-exp (online, no storage) ----
  for (int kt = 0; kt < nkt; ++kt) {
    f32x4 sc[4];
    qk_tile(Kh, ((size_t)bh * kS + kt * 64) * kDK, aq0, aq1, fr, fc, sc);
#pragma unroll
    for (int ni = 0; ni < 4; ++ni) {
      const int colg = kt * 64 + ni * 16 + fr;
#pragma unroll
      for (int r = 0; r < 4; ++r) {
        float s = sc[ni][r] * 0.125f;
        if (kt == qt && colg > rowg + fc * 4 + r) s = -1.0e30f;
        sc[ni][r] = s;
      }
    }
    float tmax[4];
#pragma unroll
    for (int r = 0; r < 4; ++r)
      tmax[r] = fmaxf(fmaxf(sc[0][r], sc[1][r]), fmaxf(sc[2][r], sc[3][r]));
#pragma unroll
    for (int off = 1; off < 16; off <<= 1)
#pragma unroll
      for (int r = 0; r < 4; ++r)
        tmax[r] = fmaxf(tmax[r], __shfl_xor(tmax[r], off));
#pragma unroll
    for (int r = 0; r < 4; ++r) {
      const float nm = fmaxf(mrow[r], tmax[r]);
      float ts = __expf(sc[0][r] - nm) + __expf(sc[1][r] - nm) +
                 __expf(sc[2][r] - nm) + __expf(sc[3][r] - nm);
#pragma unroll
      for (int off = 1; off < 16; off <<= 1) ts += __shfl_xor(ts, off);
      lrow[r] = lrow[r] * __expf(mrow[r] - nm) + ts;
      mrow[r] = nm;
    }
  }

  float invl[4];
#pragma unroll
  for (int r = 0; r < 4; ++r) invl[r] = 1.0f / lrow[r];

  f32x4 oacc[4];
  const f32x4 z4v = {0.f, 0.f, 0.f, 0.f};
#pragma unroll
  for (int ni = 0; ni < 4; ++ni) oacc[ni] = z4v;

  // ---- pass 2: P = exp(s-m)/l -> write attn fp32, LDS round-trip, PV MFMA ----
  for (int kt = 0; kt < nkt; ++kt) {
    f32x4 sc[4];
    qk_tile(Kh, ((size_t)bh * kS + kt * 64) * kDK, aq0, aq1, fr, fc, sc);
#pragma unroll
    for (int ni = 0; ni < 4; ++ni) {
      const int colg = kt * 64 + ni * 16 + fr;
#pragma unroll
      for (int r = 0; r < 4; ++r) {
        float s = sc[ni][r] * 0.125f;
        if (kt == qt && colg > rowg + fc * 4 + r) s = -1.0e30f;
        const float p = __expf(s - mrow[r]) * invl[r];
        attnp[((size_t)bh * kS + rowg + fc * 4 + r) * kS + colg] = p;
        Plds[w][fc * 4 + r][ni * 16 + fr] = (__bf16)p;  // C-layout -> LDS
      }
    }
    // PV: A-frag from LDS (A-layout), B-frag from transposed V (contiguous 16B)
#pragma unroll
    for (int kc = 0; kc < 2; ++kc) {
      bf16x8 ap = *(const bf16x8*)(&Plds[w][fr][kc * 32 + fc * 8]);
#pragma unroll
      for (int ni = 0; ni < 4; ++ni) {
        bf16x8 bv = *(const bf16x8*)(Vt + ((size_t)bh * kDK + ni * 16 + fr) * kS +
                                     kt * 64 + kc * 32 + fc * 8);
        oacc[ni] = __builtin_amdgcn_mfma_f32_16x16x32_bf16(ap, bv, oacc[ni], 0, 0, 0);
      }
    }
  }

  // ctx write: [b][s][h*64+dk] bf16 (input to output projection)
  const int b = bh >> 4, h = bh & 15;
#pragma unroll
  for (int ni = 0; ni < 4; ++ni) {
#pragma unroll
    for (int r = 0; r < 4; ++r) {
      const int srow = rowg + fc * 4 + r;
      ctxb[((size_t)b * kS + srow) * kD + h * kDK + ni * 16 + fr] = (__bf16)oacc[ni][r];
    }
  }

  // zero-fill the causally-masked columns (d_out is poisoned each call)
  const int c0 = nkt * 64;
  const int zrow = tid >> 2;   // 0..63
  const int part = tid & 3;
  float* rowp = attnp + ((size_t)bh * kS + q0 + zrow) * kS;
  const float4 zf4 = {0.f, 0.f, 0.f, 0.f};
  for (int c = c0 + part * 4; c < kS; c += 16)
    *(float4*)(rowp + c) = zf4;
}

extern "C" void kernel_launch(void* const* d_in, const int* in_sizes, int n_in,
                              void* d_out, int out_size, void* d_ws, size_t ws_size,
                              hipStream_t stream) {
  (void)in_sizes; (void)n_in; (void)out_size; (void)ws_size;
  const float* q  = (const float*)d_in[0];
  const float* k  = (const float*)d_in[1];
  const float* v  = (const float*)d_in[2];
  // d_in[3] = attn_mask: fixed causal tril, handled analytically
  const float* Wq = (const float*)d_in[4];
  const float* bq = (const float*)d_in[5];
  const float* Wk = (const float*)d_in[6];
  const float* bk = (const float*)d_in[7];
  const float* Wv = (const float*)d_in[8];
  const float* bv = (const float*)d_in[9];
  const float* Wo = (const float*)d_in[10];
  const float* bo = (const float*)d_in[11];

  float* out = (float*)d_out;                 // [B,S,D] fp32
  float* attnp = out + (size_t)kNX;           // [B,H,S,S] fp32

  char* ws = (char*)d_ws;
  __bf16* xb = (__bf16*)ws;                                        // 3*kNX bf16 (24MB)
  __bf16* wb = (__bf16*)(ws + (size_t)3 * kNX * 2);                // 4*kNW bf16 (8MB)
  __bf16* Qh = (__bf16*)(ws + (size_t)3 * kNX * 2 + (size_t)4 * kNW * 2);  // 8MB
  __bf16* Kh = Qh + (size_t)kNX;                                   // 8MB
  __bf16* Vt = Kh + (size_t)kNX;                                   // 8MB (transposed)
  __bf16* ctxb = xb;  // reuse xb: proj consumed it before attn writes ctx

  cvt_kernel<<<dim3(4096, 7), 256, 0, stream>>>(q, k, v, Wq, Wk, Wv, Wo, xb, wb);
  proj_kernel<<<dim3(8, 32, 3), 256, 0, stream>>>(xb, wb, bq, bk, bv, Qh, Kh, Vt);
  attn_kernel<<<dim3(32, 32), 256, 0, stream>>>(Qh, Kh, Vt, attnp, ctxb);
  outproj_kernel<<<dim3(8, 32), 256, 0, stream>>>(ctxb, wb + (size_t)3 * kNW, bo, out);
}

// Round 2
// 896.709 us; speedup vs baseline: 1.0749x; 1.0749x over previous
//
#include <hip/hip_runtime.h>
#include <hip/hip_bf16.h>
#include <cstdint>
#include <cstddef>

#define DEV_INLINE __device__ __forceinline__

typedef float  f32x4  __attribute__((ext_vector_type(4)));
typedef __bf16 bf16x8 __attribute__((ext_vector_type(8)));
typedef __bf16 bf16x4 __attribute__((ext_vector_type(4)));

static constexpr int kB = 2, kS = 2048, kD = 1024, kH = 16, kDK = 64;
static constexpr int kM  = kB * kS;        // 4096 rows
static constexpr int kNX = kM * kD;        // 4,194,304
static constexpr int kNW = kD * kD;        // 1,048,576

DEV_INLINE void gld16(void* lds, const void* g) {
  __builtin_amdgcn_global_load_lds(
      (const __attribute__((address_space(1))) unsigned int*)g,
      (__attribute__((address_space(3))) unsigned int*)lds, 16, 0, 0);
}

// ---------------- fp32 -> bf16 convert (q,k,v,Wq,Wk,Wv,Wo) ----------------
__global__ __launch_bounds__(256) void cvt_kernel(
    const float* __restrict__ q, const float* __restrict__ k, const float* __restrict__ v,
    const float* __restrict__ wq, const float* __restrict__ wk, const float* __restrict__ wv,
    const float* __restrict__ wo, __bf16* __restrict__ xb, __bf16* __restrict__ wb) {
  const int z = blockIdx.y;
  const float* src;
  __bf16* dst;
  int n;
  switch (z) {
    case 0:  src = q;  dst = xb;           n = kNX; break;
    case 1:  src = k;  dst = xb + kNX;     n = kNX; break;
    case 2:  src = v;  dst = xb + 2 * kNX; n = kNX; break;
    case 3:  src = wq; dst = wb;           n = kNW; break;
    case 4:  src = wk; dst = wb + kNW;     n = kNW; break;
    case 5:  src = wv; dst = wb + 2 * kNW; n = kNW; break;
    default: src = wo; dst = wb + 3 * kNW; n = kNW; break;
  }
  const int i = (blockIdx.x * 256 + threadIdx.x) * 4;
  if (i < n) {
    float4 f = *(const float4*)(src + i);
    bf16x4 o;
    o[0] = (__bf16)f.x; o[1] = (__bf16)f.y; o[2] = (__bf16)f.z; o[3] = (__bf16)f.w;
    *(bf16x4*)(dst + i) = o;
  }
}

// ---- GEMM core: C[m][n] = sum_k A[m][k]*W[n][k] + bias[n]; M=4096,N=1024,K=1024
// MODE 0: bf16 head-split [b,h,s,dk]   MODE 2: f32 [m][n]
template <int MODE>
DEV_INLINE void gemm_core(__bf16* As, __bf16* Bs,
                          const __bf16* __restrict__ A, const __bf16* __restrict__ W,
                          const float* __restrict__ bias, void* __restrict__ dstv) {
  const int tid = threadIdx.x;
  const int w = tid >> 6, l = tid & 63;
  const int m0 = blockIdx.y * 128, n0 = blockIdx.x * 128;
  const int wr = (w >> 1) * 64, wc = (w & 1) * 64;
  const int fr = l & 15, fc = l >> 4;
  const int srow = tid >> 2;         // staging row within 64-row chunk
  const int scol = (tid & 3) * 8;    // staging col (bf16 elems)

  f32x4 acc[4][4];
  const f32x4 z4 = {0.f, 0.f, 0.f, 0.f};
#pragma unroll
  for (int mi = 0; mi < 4; ++mi)
#pragma unroll
    for (int ni = 0; ni < 4; ++ni) acc[mi][ni] = z4;

  for (int k0 = 0; k0 < kD; k0 += 32) {
    __syncthreads();
    gld16(As + (size_t)(w * 64) * 8,       A + (size_t)(m0 + srow) * kD + k0 + scol);
    gld16(As + (size_t)(256 + w * 64) * 8, A + (size_t)(m0 + 64 + srow) * kD + k0 + scol);
    gld16(Bs + (size_t)(w * 64) * 8,       W + (size_t)(n0 + srow) * kD + k0 + scol);
    gld16(Bs + (size_t)(256 + w * 64) * 8, W + (size_t)(n0 + 64 + srow) * kD + k0 + scol);
    __syncthreads();
    bf16x8 af[4], bfr[4];
#pragma unroll
    for (int mi = 0; mi < 4; ++mi)
      af[mi] = *(const bf16x8*)(As + (wr + mi * 16 + fr) * 32 + fc * 8);
#pragma unroll
    for (int ni = 0; ni < 4; ++ni)
      bfr[ni] = *(const bf16x8*)(Bs + (wc + ni * 16 + fr) * 32 + fc * 8);
#pragma unroll
    for (int mi = 0; mi < 4; ++mi)
#pragma unroll
      for (int ni = 0; ni < 4; ++ni)
        acc[mi][ni] = __builtin_amdgcn_mfma_f32_16x16x32_bf16(af[mi], bfr[ni], acc[mi][ni], 0, 0, 0);
  }

#pragma unroll
  for (int mi = 0; mi < 4; ++mi) {
#pragma unroll
    for (int ni = 0; ni < 4; ++ni) {
      const int col = n0 + wc + ni * 16 + fr;
      const float bb = bias[col];
#pragma unroll
      for (int r = 0; r < 4; ++r) {
        const int row = m0 + wr + mi * 16 + fc * 4 + r;  // C-layout: row=(l>>4)*4+reg, col=l&15
        const float val = acc[mi][ni][r] + bb;
        if (MODE == 2) {
          ((float*)dstv)[(size_t)row * kD + col] = val;
        } else {
          const int b = row >> 11, s = row & (kS - 1);
          const int h = col >> 6, dk = col & 63;
          ((__bf16*)dstv)[((size_t)(b * kH + h) * kS + s) * kDK + dk] = (__bf16)val;
        }
      }
    }
  }
}

__global__ __launch_bounds__(256) void proj_kernel(
    const __bf16* __restrict__ xb, const __bf16* __restrict__ wb,
    const float* __restrict__ bq, const float* __restrict__ bk, const float* __restrict__ bv,
    __bf16* __restrict__ Qh, __bf16* __restrict__ Kh, __bf16* __restrict__ Vh) {
  __shared__ __attribute__((aligned(16))) __bf16 As[128 * 32];
  __shared__ __attribute__((aligned(16))) __bf16 Bs[128 * 32];
  const int z = blockIdx.z;
  const __bf16* A = xb + (size_t)z * kNX;
  const __bf16* W = wb + (size_t)z * kNW;
  if (z == 0)      gemm_core<0>(As, Bs, A, W, bq, Qh);
  else if (z == 1) gemm_core<0>(As, Bs, A, W, bk, Kh);
  else             gemm_core<0>(As, Bs, A, W, bv, Vh);
}

// V head-split [bh][s][dk] -> transposed [bh][dk][s] via LDS tile transpose
__global__ __launch_bounds__(256) void vtrans_kernel(
    const __bf16* __restrict__ Vh, __bf16* __restrict__ Vt) {
  __shared__ __bf16 T[64][65];
  const int bh = blockIdx.y, st = blockIdx.x;
  const int t = threadIdx.x;
  const int r = t >> 3, c8 = (t & 7) * 8;
  const size_t base = (size_t)bh * kS * kDK;
#pragma unroll
  for (int rr = 0; rr < 64; rr += 32) {
    bf16x8 v = *(const bf16x8*)(Vh + base + (size_t)(st * 64 + r + rr) * kDK + c8);
#pragma unroll
    for (int j = 0; j < 8; ++j) T[r + rr][c8 + j] = v[j];
  }
  __syncthreads();
#pragma unroll
  for (int rr = 0; rr < 64; rr += 32) {
    bf16x8 o;
#pragma unroll
    for (int j = 0; j < 8; ++j) o[j] = T[c8 + j][r + rr];
    *(bf16x8*)(Vt + base + (size_t)(r + rr) * kS + st * 64 + c8) = o;
  }
}

__global__ __launch_bounds__(256) void outproj_kernel(
    const __bf16* __restrict__ ctxb, const __bf16* __restrict__ wo,
    const float* __restrict__ bo, float* __restrict__ out) {
  __shared__ __attribute__((aligned(16))) __bf16 As[128 * 32];
  __shared__ __attribute__((aligned(16))) __bf16 Bs[128 * 32];
  gemm_core<2>(As, Bs, ctxb, wo, bo, out);
}

// ---------------- fused causal attention ----------------
// Block: 512 threads = 8 waves. Waves 0-3 -> q-tile pairIdx, waves 4-7 -> q-tile 31-pairIdx.
// Each wave owns 16 Q rows. Work per block = 33 K-tiles x 2 passes (perfectly balanced).
DEV_INLINE void qk_tile(const __bf16* __restrict__ Kh, size_t ktile_base,
                        bf16x8 aq0, bf16x8 aq1, int fr, int fc, f32x4 sc[4]) {
  const f32x4 z4 = {0.f, 0.f, 0.f, 0.f};
#pragma unroll
  for (int ni = 0; ni < 4; ++ni) sc[ni] = z4;
#pragma unroll
  for (int kc = 0; kc < 2; ++kc) {
    bf16x8 aq = kc ? aq1 : aq0;
#pragma unroll
    for (int ni = 0; ni < 4; ++ni) {
      bf16x8 bk = *(const bf16x8*)(Kh + ktile_base + (size_t)(ni * 16 + fr) * kDK + kc * 32 + fc * 8);
      sc[ni] = __builtin_amdgcn_mfma_f32_16x16x32_bf16(aq, bk, sc[ni], 0, 0, 0);
    }
  }
}

__global__ __launch_bounds__(512, 4) void attn_kernel(
    const __bf16* __restrict__ Qh, const __bf16* __restrict__ Kh,
    const __bf16* __restrict__ Vt, float* __restrict__ attnp,
    __bf16* __restrict__ ctxb) {
  __shared__ __attribute__((aligned(16))) __bf16 Plds[8][16][72];
  const int pair = blockIdx.x, bh = blockIdx.y;
  const int tid = threadIdx.x, w = tid >> 6, l = tid & 63;
  const int wg = w >> 2, wi = w & 3;
  const int qt = wg ? (31 - pair) : pair;
  const int q0 = qt * 64;
  const int rowg = q0 + wi * 16;
  const int fr = l & 15, fc = l >> 4;
  const size_t kbase = (size_t)bh * kS * kDK;

  const __bf16* qptr = Qh + (kbase + (size_t)(rowg + fr) * kDK) + fc * 8;
  const bf16x8 aq0 = *(const bf16x8*)(qptr);
  const bf16x8 aq1 = *(const bf16x8*)(qptr + 32);

  float mrow[4], lrow[4];
#pragma unroll
  for (int r = 0; r < 4; ++r) { mrow[r] = -1.0e30f; lrow[r] = 0.f; }

  // ---- pass 1: exact row max and sum-of-exp; tiles [0,qt) unmasked, tile qt masked ----
  int kt = 0;
  for (; kt + 2 <= qt; kt += 2) {
    f32x4 s0[4], s1[4];
    qk_tile(Kh, kbase + (size_t)kt * 64 * kDK, aq0, aq1, fr, fc, s0);
    qk_tile(Kh, kbase + (size_t)(kt + 1) * 64 * kDK, aq0, aq1, fr, fc, s1);
#pragma unroll
    for (int ni = 0; ni < 4; ++ni)
#pragma unroll
      for (int r = 0; r < 4; ++r) { s0[ni][r] *= 0.125f; s1[ni][r] *= 0.125f; }
    float tmax[4];
#pragma unroll
    for (int r = 0; r < 4; ++r)
      tmax[r] = fmaxf(fmaxf(fmaxf(s0[0][r], s0[1][r]), fmaxf(s0[2][r], s0[3][r])),
                      fmaxf(fmaxf(s1[0][r], s1[1][r]), fmaxf(s1[2][r], s1[3][r])));
#pragma unroll
    for (int off = 1; off < 16; off <<= 1)
#pragma unroll
      for (int r = 0; r < 4; ++r)
        tmax[r] = fmaxf(tmax[r], __shfl_xor(tmax[r], off));
#pragma unroll
    for (int r = 0; r < 4; ++r) {
      const float nm = fmaxf(mrow[r], tmax[r]);
      float ts = __expf(s0[0][r] - nm) + __expf(s0[1][r] - nm) +
                 __expf(s0[2][r] - nm) + __expf(s0[3][r] - nm) +
                 __expf(s1[0][r] - nm) + __expf(s1[1][r] - nm) +
                 __expf(s1[2][r] - nm) + __expf(s1[3][r] - nm);
#pragma unroll
      for (int off = 1; off < 16; off <<= 1) ts += __shfl_xor(ts, off);
      lrow[r] = lrow[r] * __expf(mrow[r] - nm) + ts;
      mrow[r] = nm;
    }
  }
  for (; kt <= qt; ++kt) {  // remainder unmasked tile (if any) + diagonal masked tile
    f32x4 sc[4];
    qk_tile(Kh, kbase + (size_t)kt * 64 * kDK, aq0, aq1, fr, fc, sc);
#pragma unroll
    for (int ni = 0; ni < 4; ++ni) {
      const int colg = kt * 64 + ni * 16 + fr;
#pragma unroll
      for (int r = 0; r < 4; ++r) {
        float s = sc[ni][r] * 0.125f;
        if (kt == qt && colg > rowg + fc * 4 + r) s = -1.0e30f;
        sc[ni][r] = s;
      }
    }
    float tmax[4];
#pragma unroll
    for (int r = 0; r < 4; ++r)
      tmax[r] = fmaxf(fmaxf(sc[0][r], sc[1][r]), fmaxf(sc[2][r], sc[3][r]));
#pragma unroll
    for (int off = 1; off < 16; off <<= 1)
#pragma unroll
      for (int r = 0; r < 4; ++r)
        tmax[r] = fmaxf(tmax[r], __shfl_xor(tmax[r], off));
#pragma unroll
    for (int r = 0; r < 4; ++r) {
      const float nm = fmaxf(mrow[r], tmax[r]);
      float ts = __expf(sc[0][r] - nm) + __expf(sc[1][r] - nm) +
                 __expf(sc[2][r] - nm) + __expf(sc[3][r] - nm);
#pragma unroll
      for (int off = 1; off < 16; off <<= 1) ts += __shfl_xor(ts, off);
      lrow[r] = lrow[r] * __expf(mrow[r] - nm) + ts;
      mrow[r] = nm;
    }
  }

  float invl[4];
#pragma unroll
  for (int r = 0; r < 4; ++r) invl[r] = 1.0f / lrow[r];

  f32x4 oacc[4];
  const f32x4 z4v = {0.f, 0.f, 0.f, 0.f};
#pragma unroll
  for (int ni = 0; ni < 4; ++ni) oacc[ni] = z4v;

  // ---- pass 2: P = exp(s-m)/l -> write attn fp32, LDS round-trip, PV MFMA ----
  auto pv_tile = [&](f32x4 sc[4], int kt2, bool masked) {
#pragma unroll
    for (int ni = 0; ni < 4; ++ni) {
      const int colg = kt2 * 64 + ni * 16 + fr;
#pragma unroll
      for (int r = 0; r < 4; ++r) {
        float p;
        if (masked && colg > rowg + fc * 4 + r) p = 0.f;
        else p = __expf(sc[ni][r] * 0.125f - mrow[r]) * invl[r];
        attnp[((size_t)bh * kS + rowg + fc * 4 + r) * kS + colg] = p;
        Plds[w][fc * 4 + r][ni * 16 + fr] = (__bf16)p;
      }
    }
#pragma unroll
    for (int kc = 0; kc < 2; ++kc) {
      bf16x8 ap = *(const bf16x8*)(&Plds[w][fr][kc * 32 + fc * 8]);
#pragma unroll
      for (int ni = 0; ni < 4; ++ni) {
        bf16x8 bv = *(const bf16x8*)(Vt + kbase + (size_t)(ni * 16 + fr) * kS +
                                     kt2 * 64 + kc * 32 + fc * 8);
        oacc[ni] = __builtin_amdgcn_mfma_f32_16x16x32_bf16(ap, bv, oacc[ni], 0, 0, 0);
      }
    }
  };

  kt = 0;
  for (; kt + 2 <= qt; kt += 2) {
    f32x4 s0[4], s1[4];
    qk_tile(Kh, kbase + (size_t)kt * 64 * kDK, aq0, aq1, fr, fc, s0);
    qk_tile(Kh, kbase + (size_t)(kt + 1) * 64 * kDK, aq0, aq1, fr, fc, s1);
    pv_tile(s0, kt, false);
    pv_tile(s1, kt + 1, false);
  }
  for (; kt <= qt; ++kt) {
    f32x4 sc[4];
    qk_tile(Kh, kbase + (size_t)kt * 64 * kDK, aq0, aq1, fr, fc, sc);
    pv_tile(sc, kt, kt == qt);
  }

  // ctx write: [b][s][h*64+dk] bf16
  const int b = bh >> 4, h = bh & 15;
#pragma unroll
  for (int ni = 0; ni < 4; ++ni) {
#pragma unroll
    for (int r = 0; r < 4; ++r) {
      const int srow = rowg + fc * 4 + r;
      ctxb[((size_t)b * kS + srow) * kD + h * kDK + ni * 16 + fr] = (__bf16)oacc[ni][r];
    }
  }

  // zero-fill the causally-masked columns of this wave's 16 rows
  const int c0 = (qt + 1) * 64;
  const int zr = l >> 2, part = l & 3;
  float* rowp = attnp + ((size_t)bh * kS + rowg + zr) * kS;
  const float4 zf4 = {0.f, 0.f, 0.f, 0.f};
  for (int c = c0 + part * 4; c < kS; c += 16)
    *(float4*)(rowp + c) = zf4;
}

extern "C" void kernel_launch(void* const* d_in, const int* in_sizes, int n_in,
                              void* d_out, int out_size, void* d_ws, size_t ws_size,
                              hipStream_t stream) {
  (void)in_sizes; (void)n_in; (void)out_size; (void)ws_size;
  const float* q  = (const float*)d_in[0];
  const float* k  = (const float*)d_in[1];
  const float* v  = (const float*)d_in[2];
  const float* Wq = (const float*)d_in[4];
  const float* bq = (const float*)d_in[5];
  const float* Wk = (const float*)d_in[6];
  const float* bk = (const float*)d_in[7];
  const float* Wv = (const float*)d_in[8];
  const float* bv = (const float*)d_in[9];
  const float* Wo = (const float*)d_in[10];
  const float* bo = (const float*)d_in[11];

  float* out = (float*)d_out;                 // [B,S,D] fp32
  float* attnp = out + (size_t)kNX;           // [B,H,S,S] fp32

  char* ws = (char*)d_ws;
  __bf16* xb = (__bf16*)ws;                                        // 3*kNX bf16 (24MB)
  __bf16* wb = (__bf16*)(ws + (size_t)3 * kNX * 2);                // 4*kNW bf16 (8MB)
  __bf16* Qh = (__bf16*)(ws + (size_t)3 * kNX * 2 + (size_t)4 * kNW * 2);  // 8MB
  __bf16* Kh = Qh + (size_t)kNX;                                   // 8MB
  __bf16* Vt = Kh + (size_t)kNX;                                   // 8MB (transposed)
  __bf16* ctxb = xb;          // reuse xb: proj consumed it before attn writes ctx
  __bf16* Vh = (__bf16*)attnp;  // V head-split scratch parked in attn region (written later)

  cvt_kernel<<<dim3(4096, 7), 256, 0, stream>>>(q, k, v, Wq, Wk, Wv, Wo, xb, wb);
  proj_kernel<<<dim3(8, 32, 3), 256, 0, stream>>>(xb, wb, bq, bk, bv, Qh, Kh, Vh);
  vtrans_kernel<<<dim3(32, 32), 256, 0, stream>>>(Vh, Vt);
  attn_kernel<<<dim3(16, 32), 512, 0, stream>>>(Qh, Kh, Vt, attnp, ctxb);
  outproj_kernel<<<dim3(8, 32), 256, 0, stream>>>(ctxb, wb + (size_t)3 * kNW, bo, out);
}